// Round 1
// baseline (77.679 us; speedup 1.0000x reference)
//
#include <hip/hip_runtime.h>

// Problem constants (from reference)
#define NCLS 256
#define NDF  512
#define BSZ  1024
#define ALP  0.1f

// Math reformulation:
//   score[b,c] = s1[b,c] - s1[b,t] + 0.5*ALP*(R[t,c] - R[t,t]),  t = gt[b]
//   s1[b,c] = sum_d fc[c,d]*df[b,d]                       (GEMM1: 1024x256x512)
//   R[t,c]  = sum_d fc[c,d]^2*var[t,d] - 2*fc[c,d]*fc[t,d]*var[t,d]
//                                                          (GEMM2: 256x256x1024, fused operands)
//   var = faithful sequential per-class running-var recurrence from the reference.

// ---------------------------------------------------------------------------
// Kernel 1: per-class running var. One block per class, one thread per dim.
// The reference scan is sequential per class; classes are independent.
__global__ __launch_bounds__(512) void stats_kernel(const float* __restrict__ df,
                                                    const int* __restrict__ gt,
                                                    float* __restrict__ var) {
    __shared__ int gts[BSZ];
    const int cls = blockIdx.x;
    const int d = threadIdx.x;
    for (int i = threadIdx.x; i < BSZ; i += 512) gts[i] = gt[i];
    __syncthreads();

    float m = 0.f, v = 0.f;
    int n = 0;
    for (int b4 = 0; b4 < BSZ; b4 += 4) {
        const int4 g = *(const int4*)&gts[b4];  // broadcast LDS read, block-uniform
        if (g.x == cls || g.y == cls || g.z == cls || g.w == cls) {
            const int gv[4] = {g.x, g.y, g.z, g.w};
#pragma unroll
            for (int j = 0; j < 4; ++j) {
                if (gv[j] == cls) {
                    const float f = df[(b4 + j) * NDF + d];
                    const float nf = (float)n;
                    const float c1 = nf / (nf + 1.0f);
                    const float c2 = 1.0f / (nf + 1.0f);
                    m = m * c1 + f * c2;        // == f exactly when n==0 (c1=0,c2=1)
                    const float a = f - m;
                    v = v * c1 + (a * a) * (c1 * c2);
                    ++n;
                }
            }
        }
    }
    var[cls * NDF + d] = v;  // v==0 for classes with no samples
}

// ---------------------------------------------------------------------------
// Kernel 2: s1 = df @ fc^T.  Row-major A[M][K], B[N][K]; 32x32 tile, BK=32,
// 256 threads, 2x2 outputs/thread. LDS stored k-major-transposed [k][m] with
// pad 2 -> conflict-free, 8B-aligned float2 fragment reads.
template <int M, int N, int K>
__global__ __launch_bounds__(256) void gemm_abt(const float* __restrict__ A,
                                                const float* __restrict__ Bm,
                                                float* __restrict__ C) {
    __shared__ float As[32][34];
    __shared__ float Bs[32][34];
    const int tid = threadIdx.x;
    const int bm = blockIdx.x;
    const int bn = blockIdx.y;
    const int lrow = tid >> 3;          // 0..31
    const int lk4 = (tid & 7) << 2;     // 0,4,...,28
    const float* Ag = A + (bm * 32 + lrow) * K + lk4;
    const float* Bg = Bm + (bn * 32 + lrow) * K + lk4;
    const int tx = tid & 15;
    const int ty = tid >> 4;

    float acc00 = 0.f, acc01 = 0.f, acc10 = 0.f, acc11 = 0.f;
    for (int k0 = 0; k0 < K; k0 += 32) {
        const float4 av = *(const float4*)(Ag + k0);
        const float4 bv = *(const float4*)(Bg + k0);
        __syncthreads();
        As[lk4 + 0][lrow] = av.x; As[lk4 + 1][lrow] = av.y;
        As[lk4 + 2][lrow] = av.z; As[lk4 + 3][lrow] = av.w;
        Bs[lk4 + 0][lrow] = bv.x; Bs[lk4 + 1][lrow] = bv.y;
        Bs[lk4 + 2][lrow] = bv.z; Bs[lk4 + 3][lrow] = bv.w;
        __syncthreads();
#pragma unroll
        for (int kk = 0; kk < 32; ++kk) {
            const float2 af = *(const float2*)&As[kk][ty * 2];
            const float2 bf = *(const float2*)&Bs[kk][tx * 2];
            acc00 += af.x * bf.x; acc01 += af.x * bf.y;
            acc10 += af.y * bf.x; acc11 += af.y * bf.y;
        }
    }
    float* Cp = C + (bm * 32 + ty * 2) * N + bn * 32 + tx * 2;
    Cp[0] = acc00; Cp[1] = acc01;
    Cp[N] = acc10; Cp[N + 1] = acc11;
}

// ---------------------------------------------------------------------------
// Kernel 3: R[t][c] over K=1024 with operands built on the fly:
//   k <  512: A = -2*fc[t,k]*var[t,k],  B = fc[c,k]
//   k >= 512: A = var[t,k-512],         B = fc[c,k-512]^2
__global__ __launch_bounds__(256) void gemm2_kernel(const float* __restrict__ fc,
                                                    const float* __restrict__ var,
                                                    float* __restrict__ R) {
    __shared__ float As[32][34];
    __shared__ float Bs[32][34];
    const int tid = threadIdx.x;
    const int bm = blockIdx.x;   // t tile
    const int bn = blockIdx.y;   // c tile
    const int lrow = tid >> 3;
    const int lk4 = (tid & 7) << 2;
    const int arow = bm * 32 + lrow;
    const int brow = bn * 32 + lrow;
    const int tx = tid & 15;
    const int ty = tid >> 4;

    float acc00 = 0.f, acc01 = 0.f, acc10 = 0.f, acc11 = 0.f;
    for (int k0 = 0; k0 < 2 * NDF; k0 += 32) {
        float4 av, bv;
        if (k0 < NDF) {   // uniform branch
            const int ko = k0 + lk4;
            const float4 ft = *(const float4*)(fc + arow * NDF + ko);
            const float4 vt = *(const float4*)(var + arow * NDF + ko);
            av.x = -2.f * ft.x * vt.x; av.y = -2.f * ft.y * vt.y;
            av.z = -2.f * ft.z * vt.z; av.w = -2.f * ft.w * vt.w;
            bv = *(const float4*)(fc + brow * NDF + ko);
        } else {
            const int ko = k0 - NDF + lk4;
            av = *(const float4*)(var + arow * NDF + ko);
            const float4 fcv = *(const float4*)(fc + brow * NDF + ko);
            bv.x = fcv.x * fcv.x; bv.y = fcv.y * fcv.y;
            bv.z = fcv.z * fcv.z; bv.w = fcv.w * fcv.w;
        }
        __syncthreads();
        As[lk4 + 0][lrow] = av.x; As[lk4 + 1][lrow] = av.y;
        As[lk4 + 2][lrow] = av.z; As[lk4 + 3][lrow] = av.w;
        Bs[lk4 + 0][lrow] = bv.x; Bs[lk4 + 1][lrow] = bv.y;
        Bs[lk4 + 2][lrow] = bv.z; Bs[lk4 + 3][lrow] = bv.w;
        __syncthreads();
#pragma unroll
        for (int kk = 0; kk < 32; ++kk) {
            const float2 af = *(const float2*)&As[kk][ty * 2];
            const float2 bf = *(const float2*)&Bs[kk][tx * 2];
            acc00 += af.x * bf.x; acc01 += af.x * bf.y;
            acc10 += af.y * bf.x; acc11 += af.y * bf.y;
        }
    }
    float* Cp = R + (bm * 32 + ty * 2) * NCLS + bn * 32 + tx * 2;
    Cp[0] = acc00; Cp[1] = acc01;
    Cp[NCLS] = acc10; Cp[NCLS + 1] = acc11;
}

// ---------------------------------------------------------------------------
// Kernel 4: epilogue. score[b,c] = (s1[b,c]-s1[b,t]) + 0.5*ALP*(R[t,c]-R[t,t])
__global__ __launch_bounds__(256) void epilogue_kernel(const float* __restrict__ s1,
                                                       const float* __restrict__ R,
                                                       const int* __restrict__ gt,
                                                       float* __restrict__ out) {
    const int b = blockIdx.x;
    const int c = threadIdx.x;
    const int t = gt[b];
    const float bias1 = s1[b * NCLS + t];   // broadcast
    const float bias2 = R[t * NCLS + t];    // broadcast
    out[b * NCLS + c] = (s1[b * NCLS + c] - bias1) + 0.5f * ALP * (R[t * NCLS + c] - bias2);
}

// ---------------------------------------------------------------------------
extern "C" void kernel_launch(void* const* d_in, const int* in_sizes, int n_in,
                              void* d_out, int out_size, void* d_ws, size_t ws_size,
                              hipStream_t stream) {
    const float* df = (const float*)d_in[0];
    const int* gt = (const int*)d_in[1];
    const float* fc = (const float*)d_in[2];
    float* out = (float*)d_out;

    float* ws = (float*)d_ws;
    float* var = ws;                        // NCLS*NDF           = 131072 f
    float* s1 = var + NCLS * NDF;           // BSZ*NCLS           = 262144 f
    float* R = s1 + BSZ * NCLS;             // NCLS*NCLS          =  65536 f
                                            // total 1.75 MB of ws

    stats_kernel<<<NCLS, 512, 0, stream>>>(df, gt, var);
    gemm_abt<BSZ, NCLS, NDF><<<dim3(BSZ / 32, NCLS / 32), 256, 0, stream>>>(df, fc, s1);
    gemm2_kernel<<<dim3(NCLS / 32, NCLS / 32), 256, 0, stream>>>(fc, var, R);
    epilogue_kernel<<<BSZ, NCLS, 0, stream>>>(s1, R, gt, out);
}

// Round 2
// 52.072 us; speedup vs baseline: 1.4918x; 1.4918x over previous
//
#include <hip/hip_runtime.h>

// Problem constants (from reference)
#define NCLS 256
#define NDF  512
#define BSZ  1024
#define ALP  0.1f

// Math reformulation:
//   score[b,c] = s1[b,c] - s1[b,t] + 0.5*ALP*(R[t,c] - R[t,t]),  t = gt[b]
//   s1[b,c] = sum_d fc[c,d]*df[b,d]                       (GEMM1: 1024x256x512)
//   R[t,c]  = sum_d fc[c,d]^2*var[t,d] - 2*fc[c,d]*fc[t,d]*var[t,d]
//                                                          (GEMM2: 256x256x1024 virtual K)
//   var = faithful sequential per-class running-var recurrence.
//
// Round-2 structure: stats -> fat_gemm (gemm1 splitK=2 + gemm2 splitK=4 fused
// into one 768-block dispatch, register-prefetch pipelined) -> epilogue (folds
// split-K partials). Rationale: round-1 was latency-bound (gemm2 on 64 blocks,
// gemm1 at 1 wave/SIMD, loads not overlapped with compute).

// ---------------------------------------------------------------------------
// Kernel 1: per-class running var. One block per class, one thread per dim.
__global__ __launch_bounds__(512) void stats_kernel(const float* __restrict__ df,
                                                    const int* __restrict__ gt,
                                                    float* __restrict__ var) {
    __shared__ int gts[BSZ];
    const int cls = blockIdx.x;
    const int d = threadIdx.x;
    for (int i = threadIdx.x; i < BSZ; i += 512) gts[i] = gt[i];
    __syncthreads();

    float m = 0.f, v = 0.f;
    int n = 0;
    for (int b4 = 0; b4 < BSZ; b4 += 4) {
        const int4 g = *(const int4*)&gts[b4];  // block-uniform broadcast read
        if (g.x == cls || g.y == cls || g.z == cls || g.w == cls) {
            const int gv[4] = {g.x, g.y, g.z, g.w};
#pragma unroll
            for (int j = 0; j < 4; ++j) {
                if (gv[j] == cls) {
                    const float f = df[(b4 + j) * NDF + d];
                    const float nf = (float)n;
                    const float c1 = nf / (nf + 1.0f);
                    const float c2 = 1.0f / (nf + 1.0f);
                    m = m * c1 + f * c2;        // exact f when n==0 (c1=0,c2=1)
                    const float a = f - m;
                    v = v * c1 + (a * a) * (c1 * c2);
                    ++n;
                }
            }
        }
    }
    var[cls * NDF + d] = v;
}

// ---------------------------------------------------------------------------
// Kernel 2: fused split-K GEMMs, 768 blocks x 256 threads (3 blocks/CU).
//   bid <  512 : s1 partial.  bm=bid&31, bn=(bid>>5)&7, z=bid>>8 (splitK=2)
//                A = df rows (K-chunk z*256..), B = fc rows.
//   bid >= 512 : R partial.   r=bid-512; bm=r&7 (t), bn=(r>>3)&7 (c), z=r>>6
//                z in {0,1}: linear part  A=-2*fc[t,k]*var[t,k], B=fc[c,k]
//                z in {2,3}: quadratic    A=var[t,k],            B=fc[c,k]^2
// 32x32 tile, BK=32, 8 K-steps, 2x2 out/thread, k-major LDS (pad 34),
// register prefetch of next K-step's raw float4 loads before the FMA loop.
__global__ __launch_bounds__(256) void fat_gemm_kernel(const float* __restrict__ df,
                                                       const float* __restrict__ fc,
                                                       const float* __restrict__ var,
                                                       float* __restrict__ s1p,
                                                       float* __restrict__ Rp) {
    __shared__ float As[32][34];
    __shared__ float Bs[32][34];
    const int tid = threadIdx.x;
    const int bid = blockIdx.x;
    const int lrow = tid >> 3;          // 0..31
    const int lk4 = (tid & 7) << 2;     // 0,4,...,28
    const int tx = tid & 15;
    const int ty = tid >> 4;

    // mode 0: s1 (copy A,B); mode 1: R linear; mode 2: R quadratic
    int mode;
    const float* pA0;   // raw load stream 0
    const float* pA1;   // raw load stream 1 (mode 1 only)
    const float* pB0;   // raw load stream B
    float* Cp;
    if (bid < 512) {
        const int bm = bid & 31;
        const int bn = (bid >> 5) & 7;
        const int z = bid >> 8;
        mode = 0;
        pA0 = df + (bm * 32 + lrow) * NDF + z * 256 + lk4;
        pA1 = pA0;  // unused
        pB0 = fc + (bn * 32 + lrow) * NDF + z * 256 + lk4;
        Cp = s1p + z * (BSZ * NCLS) + (bm * 32 + ty * 2) * NCLS + bn * 32 + tx * 2;
    } else {
        const int r = bid - 512;
        const int bm = r & 7;           // t tile
        const int bn = (r >> 3) & 7;    // c tile
        const int z = r >> 6;           // 0..3
        const bool quad = (z >= 2);
        const int ko0 = (quad ? (z - 2) : z) * 256 + lk4;
        mode = quad ? 2 : 1;
        const int arow = bm * 32 + lrow;
        const int brow = bn * 32 + lrow;
        if (quad) {
            pA0 = var + arow * NDF + ko0;   // A = var
            pA1 = pA0;                      // unused
        } else {
            pA0 = fc + arow * NDF + ko0;    // fc[t,k]
            pA1 = var + arow * NDF + ko0;   // var[t,k]
        }
        pB0 = fc + brow * NDF + ko0;        // fc[c,k]
        Cp = Rp + z * (NCLS * NCLS) + (bm * 32 + ty * 2) * NCLS + bn * 32 + tx * 2;
    }
    const int cstride = (bid < 512) ? NCLS : NCLS;  // both 256

    float acc00 = 0.f, acc01 = 0.f, acc10 = 0.f, acc11 = 0.f;
    float4 p0, p1, p2;

    // prefetch K-step 0 (raw loads only; transforms at LDS-write time)
    p0 = *(const float4*)pA0;
    p2 = *(const float4*)pB0;
    if (mode == 1) p1 = *(const float4*)pA1;

#pragma unroll 1
    for (int i = 0; i < 8; ++i) {
        float4 av, bv;
        if (mode == 0) {
            av = p0; bv = p2;
        } else if (mode == 1) {
            av.x = -2.f * p0.x * p1.x; av.y = -2.f * p0.y * p1.y;
            av.z = -2.f * p0.z * p1.z; av.w = -2.f * p0.w * p1.w;
            bv = p2;
        } else {
            av = p0;
            bv.x = p2.x * p2.x; bv.y = p2.y * p2.y;
            bv.z = p2.z * p2.z; bv.w = p2.w * p2.w;
        }
        __syncthreads();            // previous iteration's readers done
        As[lk4 + 0][lrow] = av.x; As[lk4 + 1][lrow] = av.y;
        As[lk4 + 2][lrow] = av.z; As[lk4 + 3][lrow] = av.w;
        Bs[lk4 + 0][lrow] = bv.x; Bs[lk4 + 1][lrow] = bv.y;
        Bs[lk4 + 2][lrow] = bv.z; Bs[lk4 + 3][lrow] = bv.w;
        __syncthreads();
        if (i < 7) {                // issue next loads before compute
            const int off = (i + 1) * 32;
            p0 = *(const float4*)(pA0 + off);
            p2 = *(const float4*)(pB0 + off);
            if (mode == 1) p1 = *(const float4*)(pA1 + off);
        }
#pragma unroll
        for (int kk = 0; kk < 32; ++kk) {
            const float2 af = *(const float2*)&As[kk][ty * 2];
            const float2 bf = *(const float2*)&Bs[kk][tx * 2];
            acc00 += af.x * bf.x; acc01 += af.x * bf.y;
            acc10 += af.y * bf.x; acc11 += af.y * bf.y;
        }
    }
    Cp[0] = acc00; Cp[1] = acc01;
    Cp[cstride] = acc10; Cp[cstride + 1] = acc11;
}

// ---------------------------------------------------------------------------
// Kernel 3: epilogue, folds split-K partials.
// score[b,c] = (s1[b,c]-s1[b,t]) + 0.5*ALP*(R[t,c]-R[t,t])
__global__ __launch_bounds__(256) void epilogue_kernel(const float* __restrict__ s1p,
                                                       const float* __restrict__ Rp,
                                                       const int* __restrict__ gt,
                                                       float* __restrict__ out) {
    __shared__ float sv1[NCLS];
    __shared__ float svR[NCLS];
    const int b = blockIdx.x;
    const int c = threadIdx.x;
    const int t = gt[b];
    const float v1 = s1p[b * NCLS + c] + s1p[BSZ * NCLS + b * NCLS + c];
    const float vR = Rp[t * NCLS + c]
                   + Rp[1 * NCLS * NCLS + t * NCLS + c]
                   + Rp[2 * NCLS * NCLS + t * NCLS + c]
                   + Rp[3 * NCLS * NCLS + t * NCLS + c];
    sv1[c] = v1;
    svR[c] = vR;
    __syncthreads();
    out[b * NCLS + c] = (v1 - sv1[t]) + 0.5f * ALP * (vR - svR[t]);
}

// ---------------------------------------------------------------------------
extern "C" void kernel_launch(void* const* d_in, const int* in_sizes, int n_in,
                              void* d_out, int out_size, void* d_ws, size_t ws_size,
                              hipStream_t stream) {
    const float* df = (const float*)d_in[0];
    const int* gt = (const int*)d_in[1];
    const float* fc = (const float*)d_in[2];
    float* out = (float*)d_out;

    float* ws = (float*)d_ws;
    float* var = ws;                           // NCLS*NDF   = 131072 f
    float* s1p = var + NCLS * NDF;             // 2*BSZ*NCLS = 524288 f
    float* Rp = s1p + 2 * BSZ * NCLS;          // 4*NCLS*NCLS= 262144 f
                                               // total 3.5 MB of ws

    stats_kernel<<<NCLS, 512, 0, stream>>>(df, gt, var);
    fat_gemm_kernel<<<768, 256, 0, stream>>>(df, fc, var, s1p, Rp);
    epilogue_kernel<<<BSZ, NCLS, 0, stream>>>(s1p, Rp, gt, out);
}

// Round 3
// 29.641 us; speedup vs baseline: 2.6207x; 1.7568x over previous
//
#include <hip/hip_runtime.h>

#define NCLS 256
#define NDF  512
#define BSZ  1024
#define ALP  0.1f
#define LSTR 68   // LDS row stride in floats: 68*4=272 ≡ 0 (mod 16) -> aligned b128 frag reads

// score[b,c] = s1[b,c]-s1[b,t] + 0.5*ALP*(R[t,c]-R[t,t]),  t=gt[b]
//   s1 = df @ fc^T                       (1024x256x512)
//   R[t,c] = sum_d (fc[c,d]^2 - 2 fc[c,d] fc[t,d]) var[t,d]   (256x256, virtual K=1024)
// var: faithful per-class sequential recurrence, computed REDUNDANTLY inside each
// R block (64 classes x 64 dims slice, 4x duplication) -> no inter-kernel dependency.

__device__ __forceinline__ void gemm_inner(const float (*As)[LSTR], const float (*Bs)[LSTR],
                                           int tx, int ty, float4* acc) {
#pragma unroll
    for (int kk = 0; kk < 32; ++kk) {
        const float4 a = *(const float4*)&As[kk][ty * 4];
        const float4 b = *(const float4*)&Bs[kk][tx * 4];
        acc[0].x += a.x * b.x; acc[0].y += a.x * b.y; acc[0].z += a.x * b.z; acc[0].w += a.x * b.w;
        acc[1].x += a.y * b.x; acc[1].y += a.y * b.y; acc[1].z += a.y * b.z; acc[1].w += a.y * b.w;
        acc[2].x += a.z * b.x; acc[2].y += a.z * b.y; acc[2].z += a.z * b.z; acc[2].w += a.z * b.w;
        acc[3].x += a.w * b.x; acc[3].y += a.w * b.y; acc[3].z += a.w * b.z; acc[3].w += a.w * b.w;
    }
}

// grid: 384 blocks x 256 threads.
//  bid <  256: s1 partial. z=bid&3 (K chunk of 128), tile=bid>>2: bm=tile&15, bn=tile>>4.
//  bid >= 256: R partial.  r=bid-256; z=r&7 (dim chunk of 64), tile=r>>3: bm=tile&3, bn=tile>>2.
//              Block computes its own var slice (classes bm*64..+64, dims z*64..+64),
//              then 4 k-steps: 2 linear (A=-2 fc_t var, B=fc_c) + 2 quadratic (A=var, B=fc_c^2).
__global__ __launch_bounds__(256) void fused_main(const float* __restrict__ df,
                                                  const int* __restrict__ gt,
                                                  const float* __restrict__ fc,
                                                  float* __restrict__ s1p,
                                                  float* __restrict__ Rp) {
    __shared__ float As[32][LSTR];
    __shared__ float Bs[32][LSTR];
    __shared__ int gts[BSZ];
    __shared__ unsigned long long bmap[64 * 16];

    const int tid = threadIdx.x;
    const int bid = blockIdx.x;
    const int tx = tid & 15, ty = tid >> 4;

    float4 acc[4];
    acc[0] = make_float4(0.f, 0.f, 0.f, 0.f);
    acc[1] = acc[0]; acc[2] = acc[0]; acc[3] = acc[0];

    if (bid < 256) {
        // ------------------------------- s1 path -------------------------------
        const int z = bid & 3;
        const int tile = bid >> 2;
        const int bm = tile & 15, bn = tile >> 4;
        const int arow = tid >> 2;              // 0..63
        const int kq = (tid & 3) << 3;          // 0,8,16,24
        const float* Ag = df + (bm * 64 + arow) * NDF + z * 128 + kq;
        const float* Bg = fc + (bn * 64 + arow) * NDF + z * 128 + kq;

        float4 a0 = *(const float4*)Ag, a1 = *(const float4*)(Ag + 4);
        float4 b0 = *(const float4*)Bg, b1 = *(const float4*)(Bg + 4);
#pragma unroll 1
        for (int ks = 0; ks < 4; ++ks) {
            __syncthreads();
            As[kq + 0][arow] = a0.x; As[kq + 1][arow] = a0.y; As[kq + 2][arow] = a0.z; As[kq + 3][arow] = a0.w;
            As[kq + 4][arow] = a1.x; As[kq + 5][arow] = a1.y; As[kq + 6][arow] = a1.z; As[kq + 7][arow] = a1.w;
            Bs[kq + 0][arow] = b0.x; Bs[kq + 1][arow] = b0.y; Bs[kq + 2][arow] = b0.z; Bs[kq + 3][arow] = b0.w;
            Bs[kq + 4][arow] = b1.x; Bs[kq + 5][arow] = b1.y; Bs[kq + 6][arow] = b1.z; Bs[kq + 7][arow] = b1.w;
            __syncthreads();
            if (ks < 3) {
                const int off = (ks + 1) * 32;
                a0 = *(const float4*)(Ag + off); a1 = *(const float4*)(Ag + off + 4);
                b0 = *(const float4*)(Bg + off); b1 = *(const float4*)(Bg + off + 4);
            }
            gemm_inner(As, Bs, tx, ty, acc);
        }
        float* Cp = s1p + z * (BSZ * NCLS) + (bm * 64 + ty * 4) * NCLS + bn * 64 + tx * 4;
#pragma unroll
        for (int i = 0; i < 4; ++i) *(float4*)(Cp + i * NCLS) = acc[i];
    } else {
        // ------------------------------- R path --------------------------------
        const int r = bid - 256;
        const int z = r & 7;                    // dim chunk
        const int tile = r >> 3;
        const int bm = tile & 3, bn = tile >> 2;
        const int D0 = z * 64;
        const int clocal = tid >> 2;            // 0..63: class within tile
        const int dg = tid & 3;                 // 0..3: 16-dim group
        const int myclass = bm * 64 + clocal;
        const int dim0 = D0 + dg * 16;

        // stage gt, zero bitmap
        for (int i = tid; i < BSZ; i += 256) gts[i] = gt[i];
        for (int i = tid; i < 1024; i += 256) bmap[i] = 0ull;
        __syncthreads();
        // order-preserving per-class sample bitmap (64 classes x 1024 bits)
        for (int i = tid; i < BSZ; i += 256) {
            const int c = gts[i] - bm * 64;
            if ((unsigned)c < 64u) atomicOr(&bmap[c * 16 + (i >> 6)], 1ull << (i & 63));
        }
        // fc[t, dims] while bitmap builds (needed for the linear-term A operand)
        const float* fct = fc + myclass * NDF + dim0;
        float fcq[16];
        {
            const float4 q0 = ((const float4*)fct)[0], q1 = ((const float4*)fct)[1];
            const float4 q2 = ((const float4*)fct)[2], q3 = ((const float4*)fct)[3];
            fcq[0]=q0.x; fcq[1]=q0.y; fcq[2]=q0.z; fcq[3]=q0.w;
            fcq[4]=q1.x; fcq[5]=q1.y; fcq[6]=q1.z; fcq[7]=q1.w;
            fcq[8]=q2.x; fcq[9]=q2.y; fcq[10]=q2.z; fcq[11]=q2.w;
            fcq[12]=q3.x; fcq[13]=q3.y; fcq[14]=q3.z; fcq[15]=q3.w;
        }
        __syncthreads();

        // sequential running-var recurrence for (myclass, dims dim0..dim0+16)
        float m[16], v[16];
#pragma unroll
        for (int j = 0; j < 16; ++j) { m[j] = 0.f; v[j] = 0.f; }
        float nf = 0.f;
        {
            int w = 0;
            unsigned long long bits = bmap[clocal * 16];
            auto next = [&]() -> int {
                while (bits == 0ull) {
                    if (w >= 15) return -1;
                    bits = bmap[clocal * 16 + (++w)];
                }
                const int b = __ffsll((unsigned long long)bits) - 1;
                bits &= bits - 1ull;
                return (w << 6) + b;
            };
            int cur = next();
            float f[16];
            if (cur >= 0) {
                const float* p = df + cur * NDF + dim0;
                const float4 q0 = ((const float4*)p)[0], q1 = ((const float4*)p)[1];
                const float4 q2 = ((const float4*)p)[2], q3 = ((const float4*)p)[3];
                f[0]=q0.x; f[1]=q0.y; f[2]=q0.z; f[3]=q0.w;
                f[4]=q1.x; f[5]=q1.y; f[6]=q1.z; f[7]=q1.w;
                f[8]=q2.x; f[9]=q2.y; f[10]=q2.z; f[11]=q2.w;
                f[12]=q3.x; f[13]=q3.y; f[14]=q3.z; f[15]=q3.w;
            }
            while (cur >= 0) {
                const int nxt = next();
                float g[16];
                if (nxt >= 0) {   // prefetch next sample before the dependent update
                    const float* p = df + nxt * NDF + dim0;
                    const float4 q0 = ((const float4*)p)[0], q1 = ((const float4*)p)[1];
                    const float4 q2 = ((const float4*)p)[2], q3 = ((const float4*)p)[3];
                    g[0]=q0.x; g[1]=q0.y; g[2]=q0.z; g[3]=q0.w;
                    g[4]=q1.x; g[5]=q1.y; g[6]=q1.z; g[7]=q1.w;
                    g[8]=q2.x; g[9]=q2.y; g[10]=q2.z; g[11]=q2.w;
                    g[12]=q3.x; g[13]=q3.y; g[14]=q3.z; g[15]=q3.w;
                }
                const float c2 = 1.0f / (nf + 1.0f);
                const float c1 = nf * c2;
                const float c12 = c1 * c2;
#pragma unroll
                for (int j = 0; j < 16; ++j) {
                    m[j] = m[j] * c1 + f[j] * c2;     // == f when nf==0
                    const float a = f[j] - m[j];
                    v[j] = v[j] * c1 + a * a * c12;
                }
                nf += 1.0f;
#pragma unroll
                for (int j = 0; j < 16; ++j) f[j] = g[j];
                cur = nxt;
            }
        }

        // GEMM: 4 k-steps over the 64-dim chunk (2 linear + 2 quadratic)
        const int crow = tid >> 2, kq = (tid & 3) << 3;
        const float* Bg = fc + (bn * 64 + crow) * NDF + D0;
        float4 b0 = *(const float4*)(Bg + kq), b1 = *(const float4*)(Bg + kq + 4);
#pragma unroll 1
        for (int ks = 0; ks < 4; ++ks) {
            const bool quad = (ks >= 2);
            float4 w0 = b0, w1 = b1;
            if (quad) {
                w0.x *= w0.x; w0.y *= w0.y; w0.z *= w0.z; w0.w *= w0.w;
                w1.x *= w1.x; w1.y *= w1.y; w1.z *= w1.z; w1.w *= w1.w;
            }
            __syncthreads();
            if ((dg >> 1) == (ks & 1)) {   // this thread's dims fall in this k-step
                const int kb = (dg & 1) * 16;
#pragma unroll
                for (int j = 0; j < 16; ++j) {
                    As[kb + j][clocal] = quad ? v[j] : (-2.f * fcq[j] * v[j]);
                }
            }
            Bs[kq + 0][crow] = w0.x; Bs[kq + 1][crow] = w0.y; Bs[kq + 2][crow] = w0.z; Bs[kq + 3][crow] = w0.w;
            Bs[kq + 4][crow] = w1.x; Bs[kq + 5][crow] = w1.y; Bs[kq + 6][crow] = w1.z; Bs[kq + 7][crow] = w1.w;
            __syncthreads();
            if (ks < 3) {   // prefetch next step's B columns (alternate 32-dim halves)
                const int off = ((ks + 1) & 1) * 32;
                b0 = *(const float4*)(Bg + off + kq);
                b1 = *(const float4*)(Bg + off + kq + 4);
            }
            gemm_inner(As, Bs, tx, ty, acc);
        }
        float* Cp = Rp + z * (NCLS * NCLS) + (bm * 64 + ty * 4) * NCLS + bn * 64 + tx * 4;
#pragma unroll
        for (int i = 0; i < 4; ++i) *(float4*)(Cp + i * NCLS) = acc[i];
    }
}

// ---------------------------------------------------------------------------
// Epilogue: fold 4 s1 partials + 8 R partials, subtract the c=t columns.
__global__ __launch_bounds__(256) void epilogue_kernel(const float* __restrict__ s1p,
                                                       const float* __restrict__ Rp,
                                                       const int* __restrict__ gt,
                                                       float* __restrict__ out) {
    __shared__ float sv1[NCLS];
    __shared__ float svR[NCLS];
    const int b = blockIdx.x;
    const int c = threadIdx.x;
    const int t = gt[b];
    float v1 = 0.f;
#pragma unroll
    for (int zz = 0; zz < 4; ++zz) v1 += s1p[zz * (BSZ * NCLS) + b * NCLS + c];
    float vR = 0.f;
#pragma unroll
    for (int zz = 0; zz < 8; ++zz) vR += Rp[zz * (NCLS * NCLS) + t * NCLS + c];
    sv1[c] = v1;
    svR[c] = vR;
    __syncthreads();
    out[b * NCLS + c] = (v1 - sv1[t]) + 0.5f * ALP * (vR - svR[t]);
}

// ---------------------------------------------------------------------------
extern "C" void kernel_launch(void* const* d_in, const int* in_sizes, int n_in,
                              void* d_out, int out_size, void* d_ws, size_t ws_size,
                              hipStream_t stream) {
    const float* df = (const float*)d_in[0];
    const int* gt = (const int*)d_in[1];
    const float* fc = (const float*)d_in[2];
    float* out = (float*)d_out;

    float* ws = (float*)d_ws;
    float* s1p = ws;                           // 4*BSZ*NCLS  = 1,048,576 f (4 MB)
    float* Rp = s1p + 4 * BSZ * NCLS;          // 8*NCLS*NCLS =   524,288 f (2 MB)

    fused_main<<<384, 256, 0, stream>>>(df, gt, fc, s1p, Rp);
    epilogue_kernel<<<BSZ, 256, 0, stream>>>(s1p, Rp, gt, out);
}